// Round 1
// baseline (3249.059 us; speedup 1.0000x reference)
//
#include <hip/hip_runtime.h>

#define NTOK 49
#define DIMC 128
#define XPITCH 132      // floats per padded LDS row
#define KVPITCH 264     // ushorts per padded kv row (128 k + 128 v + 8 pad)
#define QK_SCALE 0.17677669529663687f

__device__ __forceinline__ unsigned short f2bf(float f) {
    unsigned int u = __float_as_uint(f);
    u += 0x7fffu + ((u >> 16) & 1u);   // round-to-nearest-even
    return (unsigned short)(u >> 16);
}
__device__ __forceinline__ float bflo(unsigned int w) { return __uint_as_float(w << 16); }
__device__ __forceinline__ float bfhi(unsigned int w) { return __uint_as_float(w & 0xffff0000u); }

__device__ __forceinline__ float dot4(float4 a, float4 b, float c) {
    c = fmaf(a.x, b.x, c); c = fmaf(a.y, b.y, c);
    c = fmaf(a.z, b.z, c); c = fmaf(a.w, b.w, c);
    return c;
}

__global__ __launch_bounds__(256) void winattn_kernel(
    const float* __restrict__ x, const float* __restrict__ mask,
    const float* __restrict__ qkv_w, const float* __restrict__ qkv_b,
    const float* __restrict__ proj_w, const float* __restrict__ proj_b,
    const float* __restrict__ bias_table, float* __restrict__ out)
{
    __shared__ float xs[NTOK * XPITCH];     // 25872 B: x tile, later attnout
    __shared__ float kvf[NTOK * XPITCH];    // 25872 B: bf16 k|v, later fp32 out stage
    unsigned short* kvs = (unsigned short*)kvf;

    const int tid  = threadIdx.x;
    const int lane = tid & 63;
    const int h    = __builtin_amdgcn_readfirstlane(tid >> 6);  // wave id = head (uniform)
    const int b    = blockIdx.x;

    // ---- Phase 0: stage x tile (49x128) into LDS, coalesced float4 ----
    const float4* xg = (const float4*)(x + (size_t)b * (NTOK * DIMC));
    for (int i = tid; i < NTOK * 32; i += 256) {
        int n = i >> 5, c4 = i & 31;
        *(float4*)&xs[n * XPITCH + c4 * 4] = xg[i];
    }
    __syncthreads();

    // ---- Phase 1: k and v (one output column per thread), bf16 into LDS ----
    // col o = tid: o<128 -> k col o (w row 128+o); o>=128 -> v col o-128 (w row 128+o)
    {
        const float4* wrow = (const float4*)(qkv_w + (size_t)(DIMC + tid) * DIMC);
        float acc[NTOK];
        #pragma unroll
        for (int n = 0; n < NTOK; ++n) acc[n] = 0.f;
        for (int c4 = 0; c4 < 32; ++c4) {
            float4 w4 = wrow[c4];
            #pragma unroll
            for (int n = 0; n < NTOK; ++n) {
                float4 x4 = *(const float4*)&xs[n * XPITCH + c4 * 4];  // broadcast
                acc[n] = dot4(x4, w4, acc[n]);
            }
        }
        float bias = qkv_b[DIMC + tid];
        #pragma unroll
        for (int n = 0; n < NTOK; ++n)
            kvs[n * KVPITCH + tid] = f2bf(acc[n] + bias);
    }
    __syncthreads();

    // ---- Phase 2: per-lane attention. wave = head, lane = query row ----
    const int nr = (lane < NTOK) ? lane : 0;   // clamp dead lanes to valid reads

    // q row (32 dims) in registers: q = x@Wq.T + bq, then * scale
    float qr[32];
    #pragma unroll
    for (int d = 0; d < 32; ++d) qr[d] = 0.f;
    {
        const float4* wq = (const float4*)(qkv_w + (size_t)h * 32 * DIMC);
        for (int c4 = 0; c4 < 32; ++c4) {
            float4 x4 = *(const float4*)&xs[nr * XPITCH + c4 * 4];
            #pragma unroll
            for (int d = 0; d < 32; ++d) {
                float4 w4 = wq[d * 32 + c4];   // uniform addr -> scalar load
                qr[d] = dot4(x4, w4, qr[d]);
            }
        }
        #pragma unroll
        for (int d = 0; d < 32; ++d)
            qr[d] = (qr[d] + qkv_b[h * 32 + d]) * QK_SCALE;
    }

    // scores s[49] in registers (+rel-pos bias +mask)
    float s[NTOK];
    {
        const int rn = nr / 7, cn = nr % 7;
        const float* maskp = mask + (size_t)(b & 63) * (NTOK * NTOK) + nr * NTOK;
        #pragma unroll
        for (int m = 0; m < NTOK; ++m) {
            float sm = 0.f;
            const uint4* kp = (const uint4*)&kvs[m * KVPITCH + h * 32];
            #pragma unroll
            for (int d8 = 0; d8 < 4; ++d8) {
                uint4 kk = kp[d8];   // broadcast read, 8 bf16
                sm = fmaf(qr[d8*8+0], bflo(kk.x), sm);
                sm = fmaf(qr[d8*8+1], bfhi(kk.x), sm);
                sm = fmaf(qr[d8*8+2], bflo(kk.y), sm);
                sm = fmaf(qr[d8*8+3], bfhi(kk.y), sm);
                sm = fmaf(qr[d8*8+4], bflo(kk.z), sm);
                sm = fmaf(qr[d8*8+5], bfhi(kk.z), sm);
                sm = fmaf(qr[d8*8+6], bflo(kk.w), sm);
                sm = fmaf(qr[d8*8+7], bfhi(kk.w), sm);
            }
            const int rm = m / 7, cm = m % 7;               // compile-time (m unrolled)
            const int idx = (rn - rm + 6) * 13 + (cn - cm + 6);
            s[m] = sm + bias_table[idx * 4 + h] + maskp[m];
        }
    }

    // lane-local softmax (normalization folded into PV epilogue)
    float mx = s[0];
    #pragma unroll
    for (int m = 1; m < NTOK; ++m) mx = fmaxf(mx, s[m]);
    float sum = 0.f;
    #pragma unroll
    for (int m = 0; m < NTOK; ++m) { float e = __expf(s[m] - mx); s[m] = e; sum += e; }
    const float inv = 1.f / sum;

    // PV: out row (32 dims) in registers
    float ov[32];
    #pragma unroll
    for (int d = 0; d < 32; ++d) ov[d] = 0.f;
    #pragma unroll
    for (int m = 0; m < NTOK; ++m) {
        float p = s[m];
        const uint4* vp = (const uint4*)&kvs[m * KVPITCH + DIMC + h * 32];
        #pragma unroll
        for (int d8 = 0; d8 < 4; ++d8) {
            uint4 vv = vp[d8];   // broadcast read, 8 bf16
            ov[d8*8+0] = fmaf(p, bflo(vv.x), ov[d8*8+0]);
            ov[d8*8+1] = fmaf(p, bfhi(vv.x), ov[d8*8+1]);
            ov[d8*8+2] = fmaf(p, bflo(vv.y), ov[d8*8+2]);
            ov[d8*8+3] = fmaf(p, bfhi(vv.y), ov[d8*8+3]);
            ov[d8*8+4] = fmaf(p, bflo(vv.z), ov[d8*8+4]);
            ov[d8*8+5] = fmaf(p, bfhi(vv.z), ov[d8*8+5]);
            ov[d8*8+6] = fmaf(p, bflo(vv.w), ov[d8*8+6]);
            ov[d8*8+7] = fmaf(p, bfhi(vv.w), ov[d8*8+7]);
        }
    }
    #pragma unroll
    for (int d = 0; d < 32; ++d) ov[d] *= inv;

    // ---- attnout -> xs (reuse; all q-phase reads of xs are done) ----
    __syncthreads();
    if (lane < NTOK) {
        #pragma unroll
        for (int d4 = 0; d4 < 8; ++d4) {
            float4 t;
            t.x = ov[d4*4+0]; t.y = ov[d4*4+1]; t.z = ov[d4*4+2]; t.w = ov[d4*4+3];
            *(float4*)&xs[lane * XPITCH + h * 32 + d4 * 4] = t;
        }
    }
    __syncthreads();

    // ---- Phase 3: proj. wave h, lane n computes out[n][h*32 .. h*32+31] ----
    float po[32];
    #pragma unroll
    for (int d = 0; d < 32; ++d) po[d] = 0.f;
    {
        const float4* wp = (const float4*)(proj_w + (size_t)h * 32 * DIMC);
        for (int c4 = 0; c4 < 32; ++c4) {
            float4 a4 = *(const float4*)&xs[nr * XPITCH + c4 * 4];
            #pragma unroll
            for (int d = 0; d < 32; ++d) {
                float4 w4 = wp[d * 32 + c4];   // uniform addr -> scalar load
                po[d] = dot4(a4, w4, po[d]);
            }
        }
    }

    // stage final fp32 into kvf (kv reads finished before previous barrier)
    if (lane < NTOK) {
        #pragma unroll
        for (int d4 = 0; d4 < 8; ++d4) {
            float4 t;
            t.x = po[d4*4+0] + proj_b[h*32 + d4*4+0];
            t.y = po[d4*4+1] + proj_b[h*32 + d4*4+1];
            t.z = po[d4*4+2] + proj_b[h*32 + d4*4+2];
            t.w = po[d4*4+3] + proj_b[h*32 + d4*4+3];
            *(float4*)&kvf[lane * XPITCH + h * 32 + d4 * 4] = t;
        }
    }
    __syncthreads();

    // ---- coalesced float4 store ----
    float4* og = (float4*)(out + (size_t)b * (NTOK * DIMC));
    for (int i = tid; i < NTOK * 32; i += 256) {
        int n = i >> 5, c4 = i & 31;
        og[i] = *(const float4*)&kvf[n * XPITCH + c4 * 4];
    }
}

extern "C" void kernel_launch(void* const* d_in, const int* in_sizes, int n_in,
                              void* d_out, int out_size, void* d_ws, size_t ws_size,
                              hipStream_t stream) {
    (void)in_sizes; (void)n_in; (void)d_ws; (void)ws_size; (void)out_size;
    const float* x          = (const float*)d_in[0];
    const float* mask       = (const float*)d_in[1];
    const float* qkv_w      = (const float*)d_in[2];
    const float* qkv_b      = (const float*)d_in[3];
    const float* proj_w     = (const float*)d_in[4];
    const float* proj_b     = (const float*)d_in[5];
    const float* bias_table = (const float*)d_in[6];
    winattn_kernel<<<4096, 256, 0, stream>>>(x, mask, qkv_w, qkv_b, proj_w, proj_b,
                                             bias_table, (float*)d_out);
}

// Round 2
// 297.844 us; speedup vs baseline: 10.9086x; 10.9086x over previous
//
#include <hip/hip_runtime.h>

#define QK_SCALE 0.17677669529663687f

typedef __attribute__((ext_vector_type(8))) short bf16x8;
typedef __attribute__((ext_vector_type(4))) short bf16x4;
typedef __attribute__((ext_vector_type(4))) float floatx4;

__device__ __forceinline__ unsigned short f2bf(float f) {
    unsigned int u = __float_as_uint(f);
    u += 0x7fffu + ((u >> 16) & 1u);   // round-to-nearest-even
    return (unsigned short)(u >> 16);
}

__device__ __forceinline__ bf16x8 ld8_2x4(const short* p) {  // 8B-aligned pair load
    union { bf16x8 v8; bf16x4 v4[2]; } u;
    u.v4[0] = *(const bf16x4*)p;
    u.v4[1] = *(const bf16x4*)(p + 4);
    return u.v8;
}

// ---- prep: bf16 weights + combined (mask + gathered rel-pos bias) table ----
// ws layout: [0, 131072) bytes: qkv_w bf16 (49152) then proj_w bf16 (16384)
//            [131072, ...): cm fp32 (64,4,49,49) = 2,458,624 bytes
__global__ __launch_bounds__(256) void prep_kernel(
    const float* __restrict__ qkv_w, const float* __restrict__ proj_w,
    const float* __restrict__ bias_table, const float* __restrict__ mask,
    unsigned short* __restrict__ wbf, float* __restrict__ cm)
{
    int g = blockIdx.x * 256 + threadIdx.x;
    if (g < 49152) {
        wbf[g] = f2bf(qkv_w[g]);
    } else if (g < 65536) {
        wbf[g] = f2bf(proj_w[g - 49152]);
    } else if (g < 680192) {
        int t = g - 65536;              // ((w*4+h)*49+i)*49+j
        int j = t % 49; int t2 = t / 49;
        int i = t2 % 49; int t3 = t2 / 49;
        int h = t3 & 3;  int wn = t3 >> 2;
        int idx = (i / 7 - j / 7 + 6) * 13 + (i % 7 - j % 7 + 6);
        cm[t] = mask[wn * 2401 + i * 49 + j] + bias_table[idx * 4 + h];
    }
}

// LDS map (shorts). Head h region base hq = h*7424 (14848 B):
//   q:  hq+0     64 rows x 40  (2560)     [dead after S MFMAs]
//   k:  hq+2560  64 rows x 40  (2560)     [dead after S MFMAs]
//   vT: hq+5120  32 rows x 72  (2304)
//   P:  hq+0     64 rows x 72  (4608)     [overlaps dead q+k]
// xs/ao: offset 0, 64 rows x 136 (8704)   [time-sliced vs head regions, barriers]
__global__ __launch_bounds__(256, 2) void winattn_mfma(
    const float* __restrict__ x,
    const float* __restrict__ qkv_b,
    const float* __restrict__ proj_b,
    const unsigned short* __restrict__ wbf,
    const float* __restrict__ cm,
    float* __restrict__ out)
{
    __shared__ __align__(16) short smem[29696];   // 59392 B

    const int tid  = threadIdx.x;
    const int lane = tid & 63;
    const int lid  = lane & 15;
    const int quad = lane >> 4;
    const int h    = tid >> 6;        // wave = head
    const int b    = blockIdx.x;
    const int w    = b & 63;
    const int hq   = h * 7424;

    // ---- Phase 0: stage x (49x128) fp32 -> bf16 LDS rows (pitch 136), pad rows zeroed ----
    {
        const float4* xg = (const float4*)(x + (size_t)b * 6272);
        for (int i = tid; i < 1568; i += 256) {       // 49*32 float4s
            int n = i >> 5, c4 = i & 31;
            float4 v = xg[i];
            ushort4 u;
            u.x = f2bf(v.x); u.y = f2bf(v.y); u.z = f2bf(v.z); u.w = f2bf(v.w);
            *(ushort4*)&smem[n * 136 + c4 * 4] = u;
        }
        ushort4 z; z.x = 0; z.y = 0; z.z = 0; z.w = 0;
        for (int i = tid; i < 510; i += 256)          // rows 49..63: 15*136/4 = 510
            *(ushort4*)&smem[49 * 136 + i * 4] = z;
    }
    __syncthreads();

    // ---- load full A tile (64x128) into registers: 16 frags ----
    bf16x8 ax[4][4];
    #pragma unroll
    for (int mt = 0; mt < 4; ++mt)
        #pragma unroll
        for (int kb = 0; kb < 4; ++kb)
            ax[mt][kb] = *(const bf16x8*)&smem[(mt * 16 + lid) * 136 + kb * 32 + quad * 8];
    __syncthreads();   // xs consumed; head regions may now be written

    const floatx4 z4 = {0.f, 0.f, 0.f, 0.f};

    // ---- QKV: wave h computes q,k,v cols [32h,32h+32) -- 6 N-tiles of 16 ----
    #pragma unroll
    for (int t = 0; t < 6; ++t) {
        const int cb = (t < 2) ? (h * 32 + t * 16)
                     : (t < 4) ? (128 + h * 32 + (t - 2) * 16)
                               : (256 + h * 32 + (t - 4) * 16);
        const unsigned short* wr = wbf + (size_t)(cb + lid) * 128 + quad * 8;
        floatx4 acc[4] = {z4, z4, z4, z4};
        #pragma unroll
        for (int kb = 0; kb < 4; ++kb) {
            bf16x8 bw = *(const bf16x8*)(wr + kb * 32);
            #pragma unroll
            for (int mt = 0; mt < 4; ++mt)
                acc[mt] = __builtin_amdgcn_mfma_f32_16x16x32_bf16(ax[mt][kb], bw, acc[mt], 0, 0, 0);
        }
        const float bias = qkv_b[cb + lid];
        #pragma unroll
        for (int mt = 0; mt < 4; ++mt) {
            #pragma unroll
            for (int r = 0; r < 4; ++r) {
                const int row = mt * 16 + quad * 4 + r;
                const float v = acc[mt][r] + bias;
                if (t < 2) {          // q (pre-scaled)
                    smem[hq + row * 40 + t * 16 + lid] = (short)f2bf(v * QK_SCALE);
                } else if (t < 4) {   // k row-major
                    smem[hq + 2560 + row * 40 + (t - 2) * 16 + lid] = (short)f2bf(v);
                } else {              // v transposed: vT[d][token]
                    smem[hq + 5120 + ((t - 4) * 16 + lid) * 72 + row] = (short)f2bf(v);
                }
            }
        }
    }

    // ---- S = q @ k^T  (per head, within wave; 16 MFMAs) ----
    bf16x8 aq[4], bk[4];
    #pragma unroll
    for (int mt = 0; mt < 4; ++mt)
        aq[mt] = ld8_2x4(&smem[hq + (mt * 16 + lid) * 40 + quad * 8]);
    #pragma unroll
    for (int nt = 0; nt < 4; ++nt)
        bk[nt] = ld8_2x4(&smem[hq + 2560 + (nt * 16 + lid) * 40 + quad * 8]);

    floatx4 sacc[4][4];
    #pragma unroll
    for (int mt = 0; mt < 4; ++mt)
        #pragma unroll
        for (int nt = 0; nt < 4; ++nt)
            sacc[mt][nt] = __builtin_amdgcn_mfma_f32_16x16x32_bf16(aq[mt], bk[nt], z4, 0, 0, 0);

    // ---- softmax in C-layout; write P (bf16) into q/k region ----
    float invs[4][4];
    const float* cmb = cm + (size_t)(w * 4 + h) * 2401;
    #pragma unroll
    for (int mt = 0; mt < 4; ++mt) {
        #pragma unroll
        for (int r = 0; r < 4; ++r) {
            const int row  = mt * 16 + quad * 4 + r;
            const int rowc = (row < 49) ? row : 48;
            float sv[4];
            #pragma unroll
            for (int nt = 0; nt < 4; ++nt) {
                const int col  = nt * 16 + lid;
                const int colc = (col < 49) ? col : 48;
                float val = sacc[mt][nt][r] + cmb[rowc * 49 + colc];
                sv[nt] = (col < 49) ? val : -1e30f;
            }
            float mx = fmaxf(fmaxf(sv[0], sv[1]), fmaxf(sv[2], sv[3]));
            #pragma unroll
            for (int d = 1; d < 16; d <<= 1) mx = fmaxf(mx, __shfl_xor(mx, d));
            float sum = 0.f;
            #pragma unroll
            for (int nt = 0; nt < 4; ++nt) { float p = __expf(sv[nt] - mx); sv[nt] = p; sum += p; }
            #pragma unroll
            for (int d = 1; d < 16; d <<= 1) sum += __shfl_xor(sum, d);
            invs[mt][r] = 1.f / sum;
            #pragma unroll
            for (int nt = 0; nt < 4; ++nt)
                smem[hq + row * 72 + nt * 16 + lid] = (short)f2bf(sv[nt]);
        }
    }

    // ---- O = P @ v  (16 MFMAs), scale rows by 1/sum ----
    bf16x8 bv[2][2];
    #pragma unroll
    for (int nt2 = 0; nt2 < 2; ++nt2)
        #pragma unroll
        for (int kb2 = 0; kb2 < 2; ++kb2)
            bv[nt2][kb2] = *(const bf16x8*)&smem[hq + 5120 + (nt2 * 16 + lid) * 72 + kb2 * 32 + quad * 8];

    floatx4 oacc[4][2] = {{z4, z4}, {z4, z4}, {z4, z4}, {z4, z4}};
    #pragma unroll
    for (int mt = 0; mt < 4; ++mt) {
        #pragma unroll
        for (int kb2 = 0; kb2 < 2; ++kb2) {
            bf16x8 ap = *(const bf16x8*)&smem[hq + (mt * 16 + lid) * 72 + kb2 * 32 + quad * 8];
            #pragma unroll
            for (int nt2 = 0; nt2 < 2; ++nt2)
                oacc[mt][nt2] = __builtin_amdgcn_mfma_f32_16x16x32_bf16(ap, bv[nt2][kb2], oacc[mt][nt2], 0, 0, 0);
        }
    }

    __syncthreads();   // all O MFMAs done everywhere; P/vT/q/k dead -> ao may overwrite

    // ---- write attn-out (bf16) to ao (pitch 136, offset 0) ----
    #pragma unroll
    for (int mt = 0; mt < 4; ++mt)
        #pragma unroll
        for (int nt2 = 0; nt2 < 2; ++nt2)
            #pragma unroll
            for (int r = 0; r < 4; ++r) {
                const int row = mt * 16 + quad * 4 + r;
                smem[row * 136 + h * 32 + nt2 * 16 + lid] =
                    (short)f2bf(oacc[mt][nt2][r] * invs[mt][r]);
            }
    __syncthreads();

    // ---- proj: C2 = ao @ proj_w.T ; wave h -> cols [32h, 32h+32) ----
    bf16x8 aa[4][4];
    #pragma unroll
    for (int mt = 0; mt < 4; ++mt)
        #pragma unroll
        for (int kb = 0; kb < 4; ++kb)
            aa[mt][kb] = *(const bf16x8*)&smem[(mt * 16 + lid) * 136 + kb * 32 + quad * 8];

    float* outb = out + (size_t)b * 6272;
    #pragma unroll
    for (int nt = 0; nt < 2; ++nt) {
        const int cb = h * 32 + nt * 16;
        const unsigned short* wr = wbf + 49152 + (size_t)(cb + lid) * 128 + quad * 8;
        floatx4 acc[4] = {z4, z4, z4, z4};
        #pragma unroll
        for (int kb = 0; kb < 4; ++kb) {
            bf16x8 bw = *(const bf16x8*)(wr + kb * 32);
            #pragma unroll
            for (int mt = 0; mt < 4; ++mt)
                acc[mt] = __builtin_amdgcn_mfma_f32_16x16x32_bf16(aa[mt][kb], bw, acc[mt], 0, 0, 0);
        }
        const float pb = proj_b[cb + lid];
        #pragma unroll
        for (int mt = 0; mt < 4; ++mt)
            #pragma unroll
            for (int r = 0; r < 4; ++r) {
                const int row = mt * 16 + quad * 4 + r;
                if (row < 49)
                    outb[row * 128 + cb + lid] = acc[mt][r] + pb;
            }
    }
}

extern "C" void kernel_launch(void* const* d_in, const int* in_sizes, int n_in,
                              void* d_out, int out_size, void* d_ws, size_t ws_size,
                              hipStream_t stream) {
    (void)in_sizes; (void)n_in; (void)out_size; (void)ws_size;
    const float* x          = (const float*)d_in[0];
    const float* mask       = (const float*)d_in[1];
    const float* qkv_w      = (const float*)d_in[2];
    const float* qkv_b      = (const float*)d_in[3];
    const float* proj_w     = (const float*)d_in[4];
    const float* proj_b     = (const float*)d_in[5];
    const float* bias_table = (const float*)d_in[6];

    unsigned short* wbf = (unsigned short*)d_ws;                 // 131072 B
    float* cm           = (float*)((char*)d_ws + 131072);        // 2,458,624 B

    prep_kernel<<<2657, 256, 0, stream>>>(qkv_w, proj_w, bias_table, mask, wbf, cm);
    winattn_mfma<<<4096, 256, 0, stream>>>(x, qkv_b, proj_b, wbf, cm, (float*)d_out);
}